// Round 8
// baseline (502.517 us; speedup 1.0000x reference)
//
#include <hip/hip_runtime.h>
#include <hip/hip_fp16.h>

#define B_   16
#define C_   64
#define N_   2048
#define M_   (B_ * N_)     // 32768 points
#define K_   20
#define KS_  20
#define OC_  64
#define NBLKF  1024        // fused grid: 1024 blocks x 256 thr = 4 blocks/CU
#define NWAVEF 4096        // waves; each handles 8 points in phase 2

// ---------------------------------------------------------------------------
// Fused single-launch kernel with MANUAL global barriers (regular launch;
// R7's hipLaunchCooperativeKernel + grid.sync() failed under the harness's
// graph capture with stale-data symptoms). Co-residency is guaranteed:
// launch_bounds(256,4) => VGPR<=128 => 4 blocks/CU x 256 CUs = 1024 = grid.
// Barrier: all-thread vmcnt drain + syncthreads; thread0: release fence ->
// agent-scope atomicAdd -> relaxed spin -> acquire fence; syncthreads.
// ---------------------------------------------------------------------------

__device__ __forceinline__ void gbar(int* cnt, int target) {
    // drain this thread's vmem (incl. inline-asm loads/stores: hardware
    // vmcnt counts them regardless of compiler knowledge)
    asm volatile("s_waitcnt vmcnt(0) lgkmcnt(0)" ::: "memory");
    __syncthreads();
    if (threadIdx.x == 0) {
        __threadfence();                                   // release: wbl2
        __hip_atomic_fetch_add(cnt, 1, __ATOMIC_RELAXED,
                               __HIP_MEMORY_SCOPE_AGENT);
        while (__hip_atomic_load(cnt, __ATOMIC_RELAXED,
                                 __HIP_MEMORY_SCOPE_AGENT) < target)
            __builtin_amdgcn_s_sleep(4);
        __threadfence();                                   // acquire: inv
    }
    __syncthreads();
}

typedef float f16v __attribute__((ext_vector_type(16)));

__device__ __forceinline__ float h2f(int u) {      // bit-exact fp16 -> fp32
    __half_raw r; r.x = (unsigned short)u;
    return __half2float(__half(r));
}

template<int V, int I>
__device__ __forceinline__ float selv(const f16v& a, const f16v& b,
                                      const f16v& c, const f16v& d,
                                      const f16v& e) {
    if constexpr (V == 0) return a[I];
    else if constexpr (V == 1) return b[I];
    else if constexpr (V == 2) return c[I];
    else if constexpr (V == 3) return d[I];
    else return e[I];
}

// one perm row (20 FMAs into acc[0..19]); KK = row index within chunk (0..3)
template<int KK, bool INIT>
__device__ __forceinline__ void rowfma(float t, float bias, float* acc,
    const f16v& a, const f16v& b, const f16v& c,
    const f16v& d, const f16v& e)
{
    #define RS_(S) { constexpr int e_ = KK * 20 + (S); \
        const float w_ = selv<e_ / 16, e_ % 16>(a, b, c, d, e); \
        acc[S] = fmaf(t, w_, INIT ? bias : acc[S]); }
    RS_(0)  RS_(1)  RS_(2)  RS_(3)  RS_(4)
    RS_(5)  RS_(6)  RS_(7)  RS_(8)  RS_(9)
    RS_(10) RS_(11) RS_(12) RS_(13) RS_(14)
    RS_(15) RS_(16) RS_(17) RS_(18) RS_(19)
    #undef RS_
}

// 4 perm rows (chunk CC) -> 80 SGPRs, data-tied wait, 4 rows of FMAs.
#define CHUNK(gar, qv, CC, INIT0) { \
    f16v sA, sB, sC, sD, sE; \
    asm volatile("s_load_dwordx16 %0, %1, %2" : "=s"(sA) : "s"(psrc), "n"((CC)*320 +   0)); \
    asm volatile("s_load_dwordx16 %0, %1, %2" : "=s"(sB) : "s"(psrc), "n"((CC)*320 +  64)); \
    asm volatile("s_load_dwordx16 %0, %1, %2" : "=s"(sC) : "s"(psrc), "n"((CC)*320 + 128)); \
    asm volatile("s_load_dwordx16 %0, %1, %2" : "=s"(sD) : "s"(psrc), "n"((CC)*320 + 192)); \
    asm volatile("s_load_dwordx16 %0, %1, %2" : "=s"(sE) : "s"(psrc), "n"((CC)*320 + 256)); \
    asm volatile("s_waitcnt lgkmcnt(0)" \
        : "+s"(sA), "+s"(sB), "+s"(sC), "+s"(sD), "+s"(sE)); \
    const float t0_ = h2f(gar[(CC)*4+0]) + qv; \
    const float t1_ = h2f(gar[(CC)*4+1]) + qv; \
    const float t2_ = h2f(gar[(CC)*4+2]) + qv; \
    const float t3_ = h2f(gar[(CC)*4+3]) + qv; \
    rowfma<0, INIT0>(t0_, bias, acc, sA, sB, sC, sD, sE); \
    rowfma<1, false>(t1_, bias, acc, sA, sB, sC, sD, sE); \
    rowfma<2, false>(t2_, bias, acc, sA, sB, sC, sD, sE); \
    rowfma<3, false>(t3_, bias, acc, sA, sB, sC, sD, sE); }

// issue ALL memory for one point: q (fp32, row ik0) then pk[0..19] (fp16).
__device__ __forceinline__ void issue_gathers(
    const __half* __restrict__ pht, const float* __restrict__ qft,
    int ivreg, int voff2, int voff4, int (&g)[21])
{
    {
        const int ik0 = __builtin_amdgcn_readlane(ivreg, 0);
        const float* spq = qft + (size_t)(unsigned)ik0 * 64u;
        asm volatile("global_load_dword %0, %1, %2"
                     : "=v"(g[20]) : "v"(voff4), "s"(spq));
    }
    #pragma unroll
    for (int k = 0; k < 20; ++k) {
        const int iku = __builtin_amdgcn_readlane(ivreg, k);
        const __half* sp = pht + (size_t)(unsigned)iku * 64u;
        asm volatile("global_load_ushort %0, %1, %2"
                     : "=v"(g[k]) : "v"(voff2), "s"(sp));
    }
}

#define WAITG(g, CNTTXT) do { \
    asm volatile("s_waitcnt vmcnt(" CNTTXT ")" : \
        "+v"(g[0]),"+v"(g[1]),"+v"(g[2]),"+v"(g[3]),"+v"(g[4]), \
        "+v"(g[5]),"+v"(g[6]),"+v"(g[7]),"+v"(g[8]),"+v"(g[9]), \
        "+v"(g[10]),"+v"(g[11]),"+v"(g[12]),"+v"(g[13]),"+v"(g[14]), \
        "+v"(g[15]),"+v"(g[16]),"+v"(g[17]),"+v"(g[18]),"+v"(g[19]), \
        "+v"(g[20])); \
    __builtin_amdgcn_sched_barrier(0); \
} while (0)

#define COMPUTE(gar, NU) { \
    const float* psrc = perm + (size_t)(NU) * 400; \
    const float qv = __int_as_float(gar[20]); \
    float acc[20]; \
    CHUNK(gar, qv, 0, true) \
    CHUNK(gar, qv, 1, false) \
    CHUNK(gar, qv, 2, false) \
    CHUNK(gar, qv, 3, false) \
    CHUNK(gar, qv, 4, false) \
    float mv = acc[0]; \
    mv = fmaxf(mv, acc[1]);  mv = fmaxf(mv, acc[2]);  mv = fmaxf(mv, acc[3]); \
    mv = fmaxf(mv, acc[4]);  mv = fmaxf(mv, acc[5]);  mv = fmaxf(mv, acc[6]); \
    mv = fmaxf(mv, acc[7]);  mv = fmaxf(mv, acc[8]);  mv = fmaxf(mv, acc[9]); \
    mv = fmaxf(mv, acc[10]); mv = fmaxf(mv, acc[11]); mv = fmaxf(mv, acc[12]); \
    mv = fmaxf(mv, acc[13]); mv = fmaxf(mv, acc[14]); mv = fmaxf(mv, acc[15]); \
    mv = fmaxf(mv, acc[16]); mv = fmaxf(mv, acc[17]); mv = fmaxf(mv, acc[18]); \
    mv = fmaxf(mv, acc[19]); \
    const float* pdst = pre + (size_t)(NU) * 64; \
    asm volatile("global_store_dword %0, %1, %2" \
                 :: "v"(voff4), "v"(mv), "s"(pdst)); \
    sum += mv; \
    sumsq = fmaf(mv, mv, sumsq); }

__global__ __launch_bounds__(256, 4) void k_fused(
    const float* __restrict__ feat,     // [B][C][N]
    const float* __restrict__ conv_w,   // [OC][2C]
    const int*   __restrict__ nidx,     // [M][K]
    const float* __restrict__ perm,     // [M][K][KS]
    const float* __restrict__ conv_b,   // [OC]
    const float* __restrict__ gamma,
    const float* __restrict__ beta,
    float* __restrict__ out,            // [B][OC][N]
    __half* __restrict__ ph,            // [M][64] fp16 P
    float*  __restrict__ qf,            // [M][64] fp32 Q
    float*  __restrict__ pre,           // [M][64]
    float*  __restrict__ partials,      // [NBLKF][128]
    float*  __restrict__ stats,         // [128]
    int*    __restrict__ barcnt)        // [3] zeroed by host memset
{
    const int tid  = threadIdx.x;
    const int lane = tid & 63;
    const int w    = tid >> 6;

    // ===================== phase 1: project (P fp16, Q fp32) ==============
    {
        const int wv = (int)blockIdx.x * 4 + w;          // 0..4095
        const int m0 = wv * 8;
        const int b0 = m0 >> 11;                         // const across 8 pts
        const float* fb = feat + (size_t)(b0 * 64 + lane) * 2048;
        const int p0 = m0 & 2047;
        const float4* cw4 = (const float4*)conv_w;
        float paq[8], qaq[8];
        #pragma unroll
        for (int h = 0; h < 2; ++h) {                    // c-half: 64 w-VGPRs
            float w2h[32], wdh[32];
            #pragma unroll
            for (int j = 0; j < 8; ++j) {
                float4 a = cw4[lane * 32 + 8 * h + j];        // W1 chunk
                float4 b = cw4[lane * 32 + 16 + 8 * h + j];   // W2 chunk
                w2h[4*j+0] = b.x; w2h[4*j+1] = b.y;
                w2h[4*j+2] = b.z; w2h[4*j+3] = b.w;
                wdh[4*j+0] = a.x - b.x; wdh[4*j+1] = a.y - b.y;
                wdh[4*j+2] = a.z - b.z; wdh[4*j+3] = a.w - b.w;
            }
            float fv = fb[p0];
            #pragma unroll
            for (int mi = 0; mi < 8; ++mi) {
                float fnext = 0.f;
                if (mi < 7) fnext = fb[p0 + mi + 1];
                float pa = 0.f, qa = 0.f;
                #pragma unroll
                for (int cc = 0; cc < 32; ++cc) {
                    float f = __int_as_float(__builtin_amdgcn_readlane(
                        __float_as_int(fv), 32 * h + cc));
                    pa = fmaf(w2h[cc], f, pa);
                    qa = fmaf(wdh[cc], f, qa);
                }
                if (h == 0) { paq[mi] = pa; qaq[mi] = qa; }
                else {
                    const int m = m0 + mi;
                    ph[(size_t)m * 64 + lane] = __float2half(paq[mi] + pa);
                    qf[(size_t)m * 64 + lane] = qaq[mi] + qa;
                }
                fv = fnext;
            }
        }
    }

    gbar(barcnt + 0, NBLKF);   // ph/qf visible grid-wide

    // ===================== phase 2: gather + conv + max ===================
    {
        const int wvu = __builtin_amdgcn_readfirstlane((int)blockIdx.x * 4 + w);
        const int voff4 = lane * 4;
        const int voff2 = lane * 2;
        float bias = conv_b[lane];
        float sum = 0.f, sumsq = 0.f;

        int iv0=0, iv1=0, iv2=0, iv3=0, iv4=0, iv5=0, iv6=0, iv7=0;
        if (lane < 20) {
            iv0 = nidx[((size_t)wvu             ) * K_ + lane];
            iv1 = nidx[((size_t)wvu +     NWAVEF) * K_ + lane];
            iv2 = nidx[((size_t)wvu + 2 * NWAVEF) * K_ + lane];
            iv3 = nidx[((size_t)wvu + 3 * NWAVEF) * K_ + lane];
            iv4 = nidx[((size_t)wvu + 4 * NWAVEF) * K_ + lane];
            iv5 = nidx[((size_t)wvu + 5 * NWAVEF) * K_ + lane];
            iv6 = nidx[((size_t)wvu + 6 * NWAVEF) * K_ + lane];
            iv7 = nidx[((size_t)wvu + 7 * NWAVEF) * K_ + lane];
        }
        // drain compiler-tracked vmem so hand vmcnt bookkeeping is exact
        asm volatile("s_waitcnt vmcnt(0)"
            : "+v"(bias), "+v"(iv0), "+v"(iv1), "+v"(iv2), "+v"(iv3),
              "+v"(iv4), "+v"(iv5), "+v"(iv6), "+v"(iv7));
        __builtin_amdgcn_sched_barrier(0);

        int gA[21], gB[21];
        issue_gathers(ph, qf, iv0, voff2, voff4, gA);
        issue_gathers(ph, qf, iv1, voff2, voff4, gB);
        WAITG(gA, "21"); COMPUTE(gA, wvu)
        issue_gathers(ph, qf, iv2, voff2, voff4, gA);
        WAITG(gB, "22"); COMPUTE(gB, wvu + NWAVEF)
        issue_gathers(ph, qf, iv3, voff2, voff4, gB);
        WAITG(gA, "22"); COMPUTE(gA, wvu + 2 * NWAVEF)
        issue_gathers(ph, qf, iv4, voff2, voff4, gA);
        WAITG(gB, "22"); COMPUTE(gB, wvu + 3 * NWAVEF)
        issue_gathers(ph, qf, iv5, voff2, voff4, gB);
        WAITG(gA, "22"); COMPUTE(gA, wvu + 4 * NWAVEF)
        issue_gathers(ph, qf, iv6, voff2, voff4, gA);
        WAITG(gB, "22"); COMPUTE(gB, wvu + 5 * NWAVEF)
        issue_gathers(ph, qf, iv7, voff2, voff4, gB);
        WAITG(gA, "22"); COMPUTE(gA, wvu + 6 * NWAVEF)
        WAITG(gB, "1");  COMPUTE(gB, wvu + 7 * NWAVEF)

        // drain asm stores (pre) before the block reduction / barrier
        asm volatile("s_waitcnt vmcnt(0)" ::: "memory");

        __shared__ float red[512];
        red[w * 128 + lane]      = sum;
        red[w * 128 + 64 + lane] = sumsq;
        __syncthreads();
        if (tid < 128) {
            float s = red[tid] + red[128 + tid] + red[256 + tid] + red[384 + tid];
            partials[(size_t)blockIdx.x * 128 + tid] = s;
        }
    }

    gbar(barcnt + 1, NBLKF);   // partials + pre visible grid-wide

    // ===================== phase 3: BN stats (blocks 0..63) ===============
    if (blockIdx.x < 64) {
        const int ch = blockIdx.x;
        double s = 0.0, s2 = 0.0;
        for (int r = tid; r < NBLKF; r += 256) {
            s  += (double)partials[(size_t)r * 128 + ch];
            s2 += (double)partials[(size_t)r * 128 + 64 + ch];
        }
        __shared__ double sh_s[256];
        __shared__ double sh_q[256];
        sh_s[tid] = s; sh_q[tid] = s2;
        __syncthreads();
        for (int off = 128; off > 0; off >>= 1) {
            if (tid < off) { sh_s[tid] += sh_s[tid + off]; sh_q[tid] += sh_q[tid + off]; }
            __syncthreads();
        }
        if (tid == 0) {
            const double inv_n = 1.0 / (double)M_;
            double mean = sh_s[0] * inv_n;
            double var  = sh_q[0] * inv_n - mean * mean;
            double inv  = 1.0 / sqrt(var + 1e-5);
            double sc   = (double)gamma[ch] * inv;
            stats[ch]      = (float)sc;
            stats[64 + ch] = (float)((double)beta[ch] - mean * sc);
        }
    }

    gbar(barcnt + 2, NBLKF);   // stats visible grid-wide

    // ===================== phase 4: scale/shift + transpose ===============
    {
        __shared__ float tile[64 * 33];
        __shared__ float scl[64];
        __shared__ float shf[64];
        if (tid < 64)       scl[tid]      = stats[tid];
        else if (tid < 128) shf[tid - 64] = stats[tid];
        __syncthreads();
        const int b  = blockIdx.x >> 6;            // 0..15
        const int pt = (blockIdx.x & 63) * 32;     // 32-point segment
        const int c  = tid & 63;
        const int r0 = tid >> 6;
        #pragma unroll
        for (int i = 0; i < 8; ++i) {
            const int r = i * 4 + r0;
            float v = pre[((size_t)(b * 2048 + pt + r)) * 64 + c];
            tile[c * 33 + r] = fmaf(v, scl[c], shf[c]);
        }
        __syncthreads();
        const int o  = tid >> 2;
        const int j0 = (tid & 3) * 8;
        #pragma unroll
        for (int j = 0; j < 8; ++j)
            out[((size_t)(b * 64 + o)) * 2048 + pt + j0 + j] = tile[o * 33 + j0 + j];
    }
}

#undef COMPUTE
#undef WAITG
#undef CHUNK

extern "C" void kernel_launch(void* const* d_in, const int* in_sizes, int n_in,
                              void* d_out, int out_size, void* d_ws, size_t ws_size,
                              hipStream_t stream) {
    const float* feat   = (const float*)d_in[0];
    const int*   nidx   = (const int*)  d_in[1];
    const float* perm   = (const float*)d_in[2];
    const float* conv_w = (const float*)d_in[3];
    const float* conv_b = (const float*)d_in[4];
    const float* gamma  = (const float*)d_in[5];
    const float* beta   = (const float*)d_in[6];
    float* out = (float*)d_out;

    char* ws = (char*)d_ws;
    const size_t off_ph   = 0;                                //  4 MiB
    const size_t off_qf   = off_ph   + (size_t)M_ * 64 * 2;   //  8 MiB
    const size_t off_pre  = off_qf   + (size_t)M_ * 64 * 4;   //  8 MiB
    const size_t off_par  = off_pre  + (size_t)M_ * 64 * 4;   // 512 KiB
    const size_t off_st   = off_par  + (size_t)NBLKF * 128 * 4; // 512 B
    const size_t off_cnt  = off_st   + 1024;                  // 12 B

    __half* ph       = (__half*)(ws + off_ph);
    float*  qf       = (float*) (ws + off_qf);
    float*  pre      = (float*) (ws + off_pre);
    float*  partials = (float*) (ws + off_par);
    float*  stats    = (float*) (ws + off_st);
    int*    barcnt   = (int*)   (ws + off_cnt);

    hipMemsetAsync(barcnt, 0, 3 * sizeof(int), stream);
    hipLaunchKernelGGL(k_fused, dim3(NBLKF), dim3(256), 0, stream,
                       feat, conv_w, nidx, perm, conv_b, gamma, beta, out,
                       ph, qf, pre, partials, stats, barcnt);
}